// Round 9
// baseline (76.651 us; speedup 1.0000x reference)
//
#include <hip/hip_runtime.h>
#include <math.h>

#define BB 4
#define CC 256
#define HH 48
#define WI 48
#define NN (HH*WI)      // 2304
#define NHEAD 8
#define HD 32
#define PLANE ((size_t)NN*HD)
#define BUF   (BB*NHEAD*NN*HD)      // 2359296 elems per [9216,256] buffer

typedef unsigned short u16;
typedef __attribute__((ext_vector_type(8))) short bf16x8;
typedef __attribute__((ext_vector_type(4))) float f32x4;

__device__ inline u16 f2bf(float f) {          // RNE float->bf16
  union { float f; unsigned u; } v; v.f = f;
  unsigned r = v.u + 0x7FFFu + ((v.u >> 16) & 1u);
  return (u16)(r >> 16);
}
__device__ inline u16 f2bf_rna(float f) {      // cheap round (f>=0)
  union { float f; unsigned u; } v; v.f = f;
  return (u16)((v.u + 0x8000u) >> 16);
}

// ---------------------------------------------------------------------------
// Fused prep: blocks [0,2304): XT[b*N+n][c] = bf16(x[b][c][n]) transpose tiles
//             blocks [2304,2624): fp32->bf16 weight convert (W1|W2|W3)
// ---------------------------------------------------------------------------
__global__ __launch_bounds__(256) void prep_kernel(
    const float* __restrict__ x, const float* __restrict__ w1,
    const float* __restrict__ w2, const float* __restrict__ w3,
    u16* __restrict__ XT, u16* __restrict__ W1b,
    u16* __restrict__ W2b, u16* __restrict__ W3b) {
  __shared__ float T[32][36];
  const int bx = blockIdx.x;
  const int t = threadIdx.x;
  if (bx < 2304) {
    const int n0 = (bx % 72) * 32, c0 = ((bx / 72) & 7) * 32, b = bx / 576;
    const int c = t >> 3, n4 = (t & 7) * 4;
    *(float4*)&T[c][n4] = *(const float4*)&x[((size_t)b * CC + c0 + c) * NN + n0 + n4];
    __syncthreads();
    const int nn = t >> 3, c4 = (t & 7) * 4;
    ushort4 o;
    o.x = f2bf(T[c4 + 0][nn]); o.y = f2bf(T[c4 + 1][nn]);
    o.z = f2bf(T[c4 + 2][nn]); o.w = f2bf(T[c4 + 3][nn]);
    *(ushort4*)&XT[((size_t)b * NN + n0 + nn) * CC + c0 + c4] = o;
  } else {
    const int i = ((bx - 2304) * 256 + t) * 4;
    const float* src; u16* dst; int off;
    if (i < 196608)      { src = w1; dst = W1b; off = i; }
    else if (i < 262144) { src = w2; dst = W2b; off = i - 196608; }
    else                 { src = w3; dst = W3b; off = i - 262144; }
    float4 v = *(const float4*)&src[off];
    ushort4 o = {f2bf(v.x), f2bf(v.y), f2bf(v.z), f2bf(v.w)};
    *(ushort4*)&dst[off] = o;
  }
}

// ---------------------------------------------------------------------------
// MFMA GEMM core 128x128 (R4-proven, used by qkv): K=256, 4 waves 2x2.
// Frag layout (HW-verified): A row=ll, B col=ll, k=lh*8+j; C/D row=lh*4+r, col=ll.
// ---------------------------------------------------------------------------
__device__ __forceinline__ void gemm_core(
    const u16* __restrict__ act, const u16* __restrict__ wb,
    int m0, int j0, u16 (&As)[128][40], u16 (&Ws)[128][40],
    f32x4 (&acc)[4][4], int tid) {
  const int lane = tid & 63, ll = lane & 15, lh = lane >> 4;
  const int wv = tid >> 6;
  const int wm = (wv >> 1) << 6, wj = (wv & 1) << 6;
  const int r_ = tid >> 1;
  const int kh = (tid & 1) << 4;
  for (int k0 = 0; k0 < CC; k0 += 32) {
    __syncthreads();
    bf16x8 a0 = *(const bf16x8*)&act[(size_t)(m0 + r_) * CC + k0 + kh];
    bf16x8 a1 = *(const bf16x8*)&act[(size_t)(m0 + r_) * CC + k0 + kh + 8];
    bf16x8 w0 = *(const bf16x8*)&wb[(size_t)(j0 + r_) * CC + k0 + kh];
    bf16x8 w1 = *(const bf16x8*)&wb[(size_t)(j0 + r_) * CC + k0 + kh + 8];
    *(bf16x8*)&As[r_][kh]     = a0;
    *(bf16x8*)&As[r_][kh + 8] = a1;
    *(bf16x8*)&Ws[r_][kh]     = w0;
    *(bf16x8*)&Ws[r_][kh + 8] = w1;
    __syncthreads();
    bf16x8 af[4], bfv[4];
#pragma unroll
    for (int s = 0; s < 4; ++s) {
      af[s]  = *(const bf16x8*)&As[wm + s * 16 + ll][lh * 8];
      bfv[s] = *(const bf16x8*)&Ws[wj + s * 16 + ll][lh * 8];
    }
#pragma unroll
    for (int ms = 0; ms < 4; ++ms)
#pragma unroll
      for (int js = 0; js < 4; ++js)
        acc[ms][js] = __builtin_amdgcn_mfma_f32_16x16x32_bf16(af[ms], bfv[js], acc[ms][js], 0, 0, 0);
  }
}

// ---------------------------------------------------------------------------
// MFMA GEMM core 64x64 (outproj/conv). 4 waves 2x2, wave = 32x32. LDS 10 KB.
// ---------------------------------------------------------------------------
__device__ __forceinline__ void gemm_core64(
    const u16* __restrict__ act, const u16* __restrict__ wb,
    int m0, int j0, u16 (&As)[64][40], u16 (&Ws)[64][40],
    f32x4 (&acc)[2][2], int tid) {
  const int lane = tid & 63, ll = lane & 15, lh = lane >> 4;
  const int wv = tid >> 6;
  const int wm = (wv >> 1) << 5, wj = (wv & 1) << 5;
  const bool isW = (tid >= 128);
  const int r_ = (tid & 127) >> 1;
  const int kh = (tid & 1) << 4;
  const u16* src = isW ? &wb[(size_t)(j0 + r_) * CC + kh]
                       : &act[(size_t)(m0 + r_) * CC + kh];
  u16* dst = isW ? &Ws[r_][kh] : &As[r_][kh];
  for (int k0 = 0; k0 < CC; k0 += 32) {
    __syncthreads();
    bf16x8 v0 = *(const bf16x8*)(src + k0);
    bf16x8 v1 = *(const bf16x8*)(src + k0 + 8);
    *(bf16x8*)dst       = v0;
    *(bf16x8*)(dst + 8) = v1;
    __syncthreads();
    bf16x8 af[2], bfv[2];
#pragma unroll
    for (int s = 0; s < 2; ++s) {
      af[s]  = *(const bf16x8*)&As[wm + s * 16 + ll][lh * 8];
      bfv[s] = *(const bf16x8*)&Ws[wj + s * 16 + ll][lh * 8];
    }
#pragma unroll
    for (int ms = 0; ms < 2; ++ms)
#pragma unroll
      for (int js = 0; js < 2; ++js)
        acc[ms][js] = __builtin_amdgcn_mfma_f32_16x16x32_bf16(af[ms], bfv[js], acc[ms][js], 0, 0, 0);
  }
}

// ---------------------------------------------------------------------------
// GEMM 1: qkv = XT @ W1^T + b1 -> Q[B,H,N,32], K[B,H,N,32], VT[B,H,32,N] (bf16)
// ---------------------------------------------------------------------------
__global__ __launch_bounds__(256) void qkv_gemm(
    const u16* __restrict__ XT, const u16* __restrict__ W1b,
    const float* __restrict__ bias,
    u16* __restrict__ Qb, u16* __restrict__ Kb, u16* __restrict__ VTb) {
  __shared__ u16 As[128][40];
  __shared__ u16 Ws[128][40];
  const int tid = threadIdx.x;
  const int m0 = blockIdx.x * 128, j0 = blockIdx.y * 128;
  f32x4 acc[4][4] = {};
  gemm_core(XT, W1b, m0, j0, As, Ws, acc, tid);

  const int lane = tid & 63, ll = lane & 15, lh = lane >> 4;
  const int wv = tid >> 6;
  const int wm = (wv >> 1) << 6, wj = (wv & 1) << 6;
  const int part = blockIdx.y >> 1;            // 0=Q 1=K 2=V (uniform)
  const int b = m0 / NN, n0 = m0 % NN;
#pragma unroll
  for (int js = 0; js < 4; ++js) {
    const int j = j0 + wj + js * 16 + ll;
    const float bj = bias[j];
    const int head = (j >> 5) & 7, d = j & 31;
#pragma unroll
    for (int ms = 0; ms < 4; ++ms) {
      const int nb = n0 + wm + ms * 16 + (lh << 2);
      if (part == 2) {
        ushort4 v = {f2bf(acc[ms][js][0] + bj), f2bf(acc[ms][js][1] + bj),
                     f2bf(acc[ms][js][2] + bj), f2bf(acc[ms][js][3] + bj)};
        *(ushort4*)&VTb[(((size_t)b * NHEAD + head) * HD + d) * NN + nb] = v;
      } else {
        u16* dst = (part == 0 ? Qb : Kb) + ((size_t)b * NHEAD + head) * PLANE;
#pragma unroll
        for (int r = 0; r < 4; ++r)
          dst[(size_t)(nb + r) * HD + d] = f2bf(acc[ms][js][r] + bj);
      }
    }
  }
}

// ---------------------------------------------------------------------------
// Wave-autonomous MFMA attention: ZERO barriers, K/V frags loaded DIRECT from
// global (L2-resident; frag layouts are 16B/lane contiguous). Only P bounces
// through a 5 KB per-wave LDS buffer (within-wave write->read, no barrier —
// proven R3-R8). Masked/out-of-range slots use CLAMPED addresses (real finite
// data) and are zeroed by the additive window mask, so no NaN can enter MFMA.
// ---------------------------------------------------------------------------
__global__ __launch_bounds__(256) void attn_mfma(
    const u16* __restrict__ Qb, const u16* __restrict__ Kb,
    const u16* __restrict__ VTb, u16* __restrict__ Ob) {
  __shared__ u16 Ps[4][16][40];   // per-wave P [q][keyslot]
  const int bid  = blockIdx.x;
  const int tile = bid % 36;
  const int head = (bid / 36) & 7;
  const int b    = bid / 288;
  const int th0 = (tile / 6) * 8, tw0 = (tile % 6) * 8;
  const int tid = threadIdx.x;
  const int wv = tid >> 6, lane = tid & 63;
  const int lh = lane >> 4, ll = lane & 15;
  const size_t plane = ((size_t)b * NHEAD + head) * PLANE;

  const int wlo = max(0, tw0 - 8);
  const int nw  = min(WI, tw0 + 16) - wlo;       // 16 or 24, block-uniform
  const bool nw24 = (nw > 16);

  // Q A-fragment
  const int qlA = (wv << 4) | ll;
  const int qhA = th0 + (qlA >> 3), qwA = tw0 + (qlA & 7);
  const bf16x8 qfrag = *(const bf16x8*)&Qb[plane + (size_t)(qhA * WI + qwA) * HD + lh * 8];

  // per-lane query coords: all 4 C/D rows share one spatial query row
  const int qh0 = th0 + (((wv << 4) + (lh << 2)) >> 3);
  int qw_r[4];
  float cb0[4], cb1[4];
  const int wk0 = wlo + ll, wk1 = wlo + 16 + ll;
#pragma unroll
  for (int r = 0; r < 4; ++r) {
    int qq = (wv << 4) + (lh << 2) + r;
    qw_r[r] = tw0 + (qq & 7);
    cb0[r] = (abs(wk0 - qw_r[r]) <= 8) ? 0.0f : -30000.0f;
    cb1[r] = (wk1 < WI && abs(wk1 - qw_r[r]) <= 8) ? 0.0f : -30000.0f;
  }

  // nw==16: key slots 16..31 always masked -> zero their P entries once
  if (!nw24) {
#pragma unroll
    for (int r = 0; r < 4; ++r)
      Ps[wv][(lh << 2) + r][16 + ll] = 0;
  }

  // clamped, loop-invariant column offsets (clamped lanes are always masked)
  const int c0idx = wk0;                    // wlo+ll <= 47 always (verified)
  const int c1idx = min(wk1, WI - 1);       // only used when nw24
  const int vb0   = min(wlo + (lh << 3), WI - 8);  // 8-key V base, clamped

  // per-row base pointers (advance by one spatial row per iter)
  const int qh0w = th0 + (wv << 1);
  const int wr_lo = max(0, qh0w - 8);
  const int wr_hi = min(HH, qh0w + 10);

  const u16* kp0 = &Kb[plane + ((size_t)(wr_lo * WI) + c0idx) * HD + (lh << 3)];
  const u16* kp1 = &Kb[plane + ((size_t)(wr_lo * WI) + c1idx) * HD + (lh << 3)];
  const u16* vp0 = &VTb[plane + (size_t)ll * NN + wr_lo * WI + vb0];
  const u16* vp1 = &VTb[plane + (size_t)(16 + ll) * NN + wr_lo * WI + vb0];
  const int kstep = WI * HD;                // elems per spatial row in K
  const int vstep = WI;                     // elems per spatial row in VT

  f32x4 o0 = {0.f, 0.f, 0.f, 0.f}, o1 = {0.f, 0.f, 0.f, 0.f};
  const f32x4 zf = {0.f, 0.f, 0.f, 0.f};
  float lsum[4] = {0.f, 0.f, 0.f, 0.f};
  const float C2 = 0.25501651847296056f;    // (1/sqrt(32)) * log2(e)

  for (int hk = wr_lo; hk < wr_hi; ++hk) {
    const bf16x8 k0 = *(const bf16x8*)kp0;
    f32x4 s0 = __builtin_amdgcn_mfma_f32_16x16x32_bf16(qfrag, k0, zf, 0, 0, 0);
    const float rb = (hk >= qh0 - 8 && hk <= qh0 + 8) ? 0.0f : -30000.0f;
    if (nw24) {
      const bf16x8 k1 = *(const bf16x8*)kp1;
      f32x4 s1 = __builtin_amdgcn_mfma_f32_16x16x32_bf16(qfrag, k1, zf, 0, 0, 0);
#pragma unroll
      for (int r = 0; r < 4; ++r) {
        float e0 = exp2f(fmaf(s0[r], C2, rb + cb0[r]));
        float e1 = exp2f(fmaf(s1[r], C2, rb + cb1[r]));
        lsum[r] += e0 + e1;
        Ps[wv][(lh << 2) + r][ll]      = f2bf_rna(e0);
        Ps[wv][(lh << 2) + r][16 + ll] = f2bf_rna(e1);
      }
    } else {
#pragma unroll
      for (int r = 0; r < 4; ++r) {
        float e0 = exp2f(fmaf(s0[r], C2, rb + cb0[r]));
        lsum[r] += e0;
        Ps[wv][(lh << 2) + r][ll] = f2bf_rna(e0);
      }
    }
    const bf16x8 pa = *(const bf16x8*)&Ps[wv][ll][lh << 3];
    const bf16x8 v0 = *(const bf16x8*)vp0;
    const bf16x8 v1 = *(const bf16x8*)vp1;
    o0 = __builtin_amdgcn_mfma_f32_16x16x32_bf16(pa, v0, o0, 0, 0, 0);
    o1 = __builtin_amdgcn_mfma_f32_16x16x32_bf16(pa, v1, o1, 0, 0, 0);
    kp0 += kstep; kp1 += kstep; vp0 += vstep; vp1 += vstep;
  }

#pragma unroll
  for (int r = 0; r < 4; ++r) {
    float s = lsum[r];
    s += __shfl_xor(s, 1); s += __shfl_xor(s, 2);
    s += __shfl_xor(s, 4); s += __shfl_xor(s, 8);
    const float inv = 1.0f / s;
    const size_t row = ((size_t)b * NN + qh0 * WI + qw_r[r]) * CC + head * HD;
    Ob[row + ll]      = f2bf(o0[r] * inv);
    Ob[row + 16 + ll] = f2bf(o1[r] * inv);
  }
}

// ---------------------------------------------------------------------------
// GEMM 2 (64x64 tiles): RES[m][c] = bf16( O @ W2^T + b2 + x[b][c][n] )
// ---------------------------------------------------------------------------
__global__ __launch_bounds__(256) void outproj_gemm(
    const u16* __restrict__ Ob, const u16* __restrict__ W2b,
    const float* __restrict__ bias, const float* __restrict__ x,
    u16* __restrict__ RESb) {
  __shared__ u16 As[64][40];
  __shared__ u16 Ws[64][40];
  const int tid = threadIdx.x;
  const int m0 = blockIdx.x * 64, j0 = blockIdx.y * 64;
  f32x4 acc[2][2] = {};
  gemm_core64(Ob, W2b, m0, j0, As, Ws, acc, tid);

  const int lane = tid & 63, ll = lane & 15, lh = lane >> 4;
  const int wv = tid >> 6;
  const int wm = (wv >> 1) << 5, wj = (wv & 1) << 5;
  const int b = m0 / NN, n0 = m0 % NN;
#pragma unroll
  for (int js = 0; js < 2; ++js) {
    const int j = j0 + wj + js * 16 + ll;
    const float bj = bias[j];
#pragma unroll
    for (int ms = 0; ms < 2; ++ms) {
      const int nb = n0 + wm + ms * 16 + (lh << 2);
      float4 xr = *(const float4*)&x[((size_t)b * CC + j) * NN + nb];
      float rr[4] = {acc[ms][js][0] + bj + xr.x, acc[ms][js][1] + bj + xr.y,
                     acc[ms][js][2] + bj + xr.z, acc[ms][js][3] + bj + xr.w};
#pragma unroll
      for (int r = 0; r < 4; ++r)
        RESb[(size_t)(m0 + wm + ms * 16 + (lh << 2) + r) * CC + j] = f2bf(rr[r]);
    }
  }
}

// ---------------------------------------------------------------------------
// GEMM 3 (64x64 tiles): out[b][c][n] = relu( RES @ W3^T + b3 )  (fp32 output)
// ---------------------------------------------------------------------------
__global__ __launch_bounds__(256) void conv_gemm(
    const u16* __restrict__ RESb, const u16* __restrict__ W3b,
    const float* __restrict__ bias, float* __restrict__ out) {
  __shared__ u16 As[64][40];
  __shared__ u16 Ws[64][40];
  const int tid = threadIdx.x;
  const int m0 = blockIdx.x * 64, j0 = blockIdx.y * 64;
  f32x4 acc[2][2] = {};
  gemm_core64(RESb, W3b, m0, j0, As, Ws, acc, tid);

  const int lane = tid & 63, ll = lane & 15, lh = lane >> 4;
  const int wv = tid >> 6;
  const int wm = (wv >> 1) << 5, wj = (wv & 1) << 5;
  const int b = m0 / NN, n0 = m0 % NN;
#pragma unroll
  for (int js = 0; js < 2; ++js) {
    const int j = j0 + wj + js * 16 + ll;
    const float bj = bias[j];
#pragma unroll
    for (int ms = 0; ms < 2; ++ms) {
      const int nb = n0 + wm + ms * 16 + (lh << 2);
      float4 v;
      v.x = fmaxf(acc[ms][js][0] + bj, 0.0f);
      v.y = fmaxf(acc[ms][js][1] + bj, 0.0f);
      v.z = fmaxf(acc[ms][js][2] + bj, 0.0f);
      v.w = fmaxf(acc[ms][js][3] + bj, 0.0f);
      *(float4*)&out[((size_t)b * CC + j) * NN + nb] = v;
    }
  }
}

extern "C" void kernel_launch(void* const* d_in, const int* in_sizes, int n_in,
                              void* d_out, int out_size, void* d_ws, size_t ws_size,
                              hipStream_t stream) {
  const float* x         = (const float*)d_in[0];
  const float* in_proj_w = (const float*)d_in[1];
  const float* in_proj_b = (const float*)d_in[2];
  const float* out_w     = (const float*)d_in[3];
  const float* out_b     = (const float*)d_in[4];
  const float* conv_w    = (const float*)d_in[5];
  const float* conv_b    = (const float*)d_in[6];
  float* out = (float*)d_out;

  u16* wsb = (u16*)d_ws;
  u16* XT   = wsb;                         // [9216][256] bf16
  u16* Qb   = wsb + (size_t)BUF;           // [B,H,N,32]
  u16* Kb   = wsb + (size_t)2 * BUF;       // [B,H,N,32]
  u16* VTb  = wsb + (size_t)3 * BUF;       // [B,H,32,N]
  u16* Ob   = wsb + (size_t)4 * BUF;       // [9216][256]
  u16* RESb = wsb + (size_t)5 * BUF;       // [9216][256]
  u16* W1b  = wsb + (size_t)6 * BUF;       // [768][256]
  u16* W2b  = W1b + 196608;                // [256][256]
  u16* W3b  = W2b + 65536;                 // [256][256]

  prep_kernel<<<dim3(2624), dim3(256), 0, stream>>>(x, in_proj_w, out_w, conv_w,
                                                    XT, W1b, W2b, W3b);
  qkv_gemm<<<dim3(72, 6), dim3(256), 0, stream>>>(XT, W1b, in_proj_b, Qb, Kb, VTb);
  attn_mfma<<<dim3(1152), dim3(256), 0, stream>>>(Qb, Kb, VTb, Ob);
  outproj_gemm<<<dim3(144, 4), dim3(256), 0, stream>>>(Ob, W2b, out_b, x, RESb);
  conv_gemm<<<dim3(144, 4), dim3(256), 0, stream>>>(RESb, W3b, conv_b, out);
}

// Round 10
// 67.402 us; speedup vs baseline: 1.1372x; 1.1372x over previous
//
#include <hip/hip_runtime.h>
#include <math.h>

#define BB 4
#define CC 256
#define HH 48
#define WI 48
#define NN (HH*WI)      // 2304
#define NHEAD 8
#define HD 32
#define PLANE ((size_t)NN*HD)
#define BUF   (BB*NHEAD*NN*HD)      // 2359296 elems per [9216,256] buffer

typedef unsigned short u16;
typedef __attribute__((ext_vector_type(8))) short bf16x8;
typedef __attribute__((ext_vector_type(4))) float f32x4;

__device__ inline u16 f2bf(float f) {          // RNE float->bf16
  union { float f; unsigned u; } v; v.f = f;
  unsigned r = v.u + 0x7FFFu + ((v.u >> 16) & 1u);
  return (u16)(r >> 16);
}
__device__ inline u16 f2bf_rna(float f) {      // cheap round (f>=0)
  union { float f; unsigned u; } v; v.f = f;
  return (u16)((v.u + 0x8000u) >> 16);
}

// ---------------------------------------------------------------------------
// Fused prep: blocks [0,2304): XT[b*N+n][c] = bf16(x[b][c][n]) transpose tiles
//             blocks [2304,2624): fp32->bf16 weight convert (W1|W2|W3)
// ---------------------------------------------------------------------------
__global__ __launch_bounds__(256) void prep_kernel(
    const float* __restrict__ x, const float* __restrict__ w1,
    const float* __restrict__ w2, const float* __restrict__ w3,
    u16* __restrict__ XT, u16* __restrict__ W1b,
    u16* __restrict__ W2b, u16* __restrict__ W3b) {
  __shared__ float T[32][36];
  const int bx = blockIdx.x;
  const int t = threadIdx.x;
  if (bx < 2304) {
    const int n0 = (bx % 72) * 32, c0 = ((bx / 72) & 7) * 32, b = bx / 576;
    const int c = t >> 3, n4 = (t & 7) * 4;
    *(float4*)&T[c][n4] = *(const float4*)&x[((size_t)b * CC + c0 + c) * NN + n0 + n4];
    __syncthreads();
    const int nn = t >> 3, c4 = (t & 7) * 4;
    ushort4 o;
    o.x = f2bf(T[c4 + 0][nn]); o.y = f2bf(T[c4 + 1][nn]);
    o.z = f2bf(T[c4 + 2][nn]); o.w = f2bf(T[c4 + 3][nn]);
    *(ushort4*)&XT[((size_t)b * NN + n0 + nn) * CC + c0 + c4] = o;
  } else {
    const int i = ((bx - 2304) * 256 + t) * 4;
    const float* src; u16* dst; int off;
    if (i < 196608)      { src = w1; dst = W1b; off = i; }
    else if (i < 262144) { src = w2; dst = W2b; off = i - 196608; }
    else                 { src = w3; dst = W3b; off = i - 262144; }
    float4 v = *(const float4*)&src[off];
    ushort4 o = {f2bf(v.x), f2bf(v.y), f2bf(v.z), f2bf(v.w)};
    *(ushort4*)&dst[off] = o;
  }
}

// ---------------------------------------------------------------------------
// MFMA GEMM core 64x64: 4 waves 2x2, wave = 32x32. LDS 10 KB, high TLP.
// Frag layout (HW-verified): A row=ll, B col=ll, k=lh*8+j; C/D row=lh*4+r, col=ll.
// ---------------------------------------------------------------------------
__device__ __forceinline__ void gemm_core64(
    const u16* __restrict__ act, const u16* __restrict__ wb,
    int m0, int j0, u16 (&As)[64][40], u16 (&Ws)[64][40],
    f32x4 (&acc)[2][2], int tid) {
  const int lane = tid & 63, ll = lane & 15, lh = lane >> 4;
  const int wv = tid >> 6;
  const int wm = (wv >> 1) << 5, wj = (wv & 1) << 5;
  const bool isW = (tid >= 128);
  const int r_ = (tid & 127) >> 1;
  const int kh = (tid & 1) << 4;
  const u16* src = isW ? &wb[(size_t)(j0 + r_) * CC + kh]
                       : &act[(size_t)(m0 + r_) * CC + kh];
  u16* dst = isW ? &Ws[r_][kh] : &As[r_][kh];
  for (int k0 = 0; k0 < CC; k0 += 32) {
    __syncthreads();
    bf16x8 v0 = *(const bf16x8*)(src + k0);
    bf16x8 v1 = *(const bf16x8*)(src + k0 + 8);
    *(bf16x8*)dst       = v0;
    *(bf16x8*)(dst + 8) = v1;
    __syncthreads();
    bf16x8 af[2], bfv[2];
#pragma unroll
    for (int s = 0; s < 2; ++s) {
      af[s]  = *(const bf16x8*)&As[wm + s * 16 + ll][lh * 8];
      bfv[s] = *(const bf16x8*)&Ws[wj + s * 16 + ll][lh * 8];
    }
#pragma unroll
    for (int ms = 0; ms < 2; ++ms)
#pragma unroll
      for (int js = 0; js < 2; ++js)
        acc[ms][js] = __builtin_amdgcn_mfma_f32_16x16x32_bf16(af[ms], bfv[js], acc[ms][js], 0, 0, 0);
  }
}

// ---------------------------------------------------------------------------
// GEMM 1 (64x64 tiles): qkv = XT @ W1^T + b1 -> Q, K [B,H,N,32], VT [B,H,32,N]
// ---------------------------------------------------------------------------
__global__ __launch_bounds__(256) void qkv_gemm(
    const u16* __restrict__ XT, const u16* __restrict__ W1b,
    const float* __restrict__ bias,
    u16* __restrict__ Qb, u16* __restrict__ Kb, u16* __restrict__ VTb) {
  __shared__ u16 As[64][40];
  __shared__ u16 Ws[64][40];
  const int tid = threadIdx.x;
  const int m0 = blockIdx.x * 64, j0 = blockIdx.y * 64;
  f32x4 acc[2][2] = {};
  gemm_core64(XT, W1b, m0, j0, As, Ws, acc, tid);

  const int lane = tid & 63, ll = lane & 15, lh = lane >> 4;
  const int wv = tid >> 6;
  const int wm = (wv >> 1) << 5, wj = (wv & 1) << 5;
  const int part = blockIdx.y >> 2;            // 0=Q 1=K 2=V (uniform)
  const int b = m0 / NN, n0 = m0 % NN;
#pragma unroll
  for (int js = 0; js < 2; ++js) {
    const int j = j0 + wj + js * 16 + ll;
    const float bj = bias[j];
    const int head = (j >> 5) & 7, d = j & 31;
#pragma unroll
    for (int ms = 0; ms < 2; ++ms) {
      const int nb = n0 + wm + ms * 16 + (lh << 2);
      if (part == 2) {
        ushort4 v = {f2bf(acc[ms][js][0] + bj), f2bf(acc[ms][js][1] + bj),
                     f2bf(acc[ms][js][2] + bj), f2bf(acc[ms][js][3] + bj)};
        *(ushort4*)&VTb[(((size_t)b * NHEAD + head) * HD + d) * NN + nb] = v;
      } else {
        u16* dst = (part == 0 ? Qb : Kb) + ((size_t)b * NHEAD + head) * PLANE;
#pragma unroll
        for (int r = 0; r < 4; ++r)
          dst[(size_t)(nb + r) * HD + d] = f2bf(acc[ms][js][r] + bj);
      }
    }
  }
}

// ---------------------------------------------------------------------------
// MFMA windowed attention (R8-proven): block-staged K/V (shared by 4 waves),
// double-buffered per-row, ONE barrier per key-row, nw==16 fast path,
// hoisted row-bias. LDS 14.3 KB -> 8 blocks/CU.
// ---------------------------------------------------------------------------
__global__ __launch_bounds__(256) void attn_mfma(
    const u16* __restrict__ Qb, const u16* __restrict__ Kb,
    const u16* __restrict__ VTb, u16* __restrict__ Ob) {
  __shared__ u16 Ks[2][32][32];   // [buf][key][dim]
  __shared__ u16 VTs[2][32][40];  // [buf][dim][key]
  __shared__ u16 Ps[4][16][40];   // per-wave P [q][key]
  const int bid  = blockIdx.x;
  const int tile = bid % 36;
  const int head = (bid / 36) & 7;
  const int b    = bid / 288;
  const int th0 = (tile / 6) * 8, tw0 = (tile % 6) * 8;
  const int tid = threadIdx.x;
  const int wv = tid >> 6, lane = tid & 63;
  const int lh = lane >> 4, ll = lane & 15;
  const size_t plane = ((size_t)b * NHEAD + head) * PLANE;

  const int wlo = max(0, tw0 - 8);
  const int nw  = min(WI, tw0 + 16) - wlo;       // 16 or 24, block-uniform
  const bool nw24 = (nw > 16);
  const int rlo = max(0, th0 - 8), rhi = min(HH, th0 + 16);

  const int qlA = (wv << 4) | ll;
  const int qhA = th0 + (qlA >> 3), qwA = tw0 + (qlA & 7);
  const bf16x8 qfrag = *(const bf16x8*)&Qb[plane + (size_t)(qhA * WI + qwA) * HD + lh * 8];

  // all 4 C/D rows of a lane share one spatial query row
  const int qh0 = th0 + (((wv << 4) + (lh << 2)) >> 3);
  int qw_r[4];
  float cb0[4], cb1[4];
  const int wk0 = wlo + ll, wk1 = wlo + 16 + ll;
#pragma unroll
  for (int r = 0; r < 4; ++r) {
    int qq = (wv << 4) + (lh << 2) + r;
    qw_r[r] = tw0 + (qq & 7);
    cb0[r] = (abs(wk0 - qw_r[r]) <= 8) ? 0.0f : -30000.0f;
    cb1[r] = (wk1 < WI && abs(wk1 - qw_r[r]) <= 8) ? 0.0f : -30000.0f;
  }

  // nw==16: key slots 16..31 always masked -> zero their P entries once
  if (!nw24) {
#pragma unroll
    for (int r = 0; r < 4; ++r)
      Ps[wv][(lh << 2) + r][16 + ll] = 0;
  }

  f32x4 o0 = {0.f, 0.f, 0.f, 0.f}, o1 = {0.f, 0.f, 0.f, 0.f};
  const f32x4 zf = {0.f, 0.f, 0.f, 0.f};
  float lsum[4] = {0.f, 0.f, 0.f, 0.f};
  const int myr_lo = th0 + (wv << 1) - 8;
  const int myr_hi = th0 + (wv << 1) + 9;
  const int sk_key = tid >> 3, sk_d = (tid & 7) * 4;   // K staging
  const int sv_d   = tid >> 3, sv_k = (tid & 7) * 4;   // VT staging
  const ushort4 zz = {0, 0, 0, 0};
  const float C2 = 0.25501651847296056f;         // (1/sqrt(32)) * log2(e)

  // stage first row into buf 0
  {
    ushort4 kv = zz, vv = zz;
    if (sk_key < nw)
      kv = *(const ushort4*)&Kb[plane + (size_t)(rlo * WI + wlo + sk_key) * HD + sk_d];
    if (sv_k < nw)
      vv = *(const ushort4*)&VTb[plane + (size_t)sv_d * NN + rlo * WI + wlo + sv_k];
    *(ushort4*)&Ks[0][sk_key][sk_d] = kv;
    *(ushort4*)&VTs[0][sv_d][sv_k] = vv;
  }

  int cur = 0;
  for (int hk = rlo; hk < rhi; ++hk) {
    ushort4 nkv = zz, nvv = zz;
    const bool more = (hk + 1 < rhi);
    if (more) {
      if (sk_key < nw)
        nkv = *(const ushort4*)&Kb[plane + (size_t)((hk + 1) * WI + wlo + sk_key) * HD + sk_d];
      if (sv_k < nw)
        nvv = *(const ushort4*)&VTb[plane + (size_t)sv_d * NN + (hk + 1) * WI + wlo + sv_k];
    }
    __syncthreads();   // buf[cur] complete
    if (hk >= myr_lo && hk <= myr_hi) {            // wave-uniform
      const float rb = (hk >= qh0 - 8 && hk <= qh0 + 8) ? 0.0f : -30000.0f;
      const bf16x8 k0 = *(const bf16x8*)&Ks[cur][ll][lh * 8];
      f32x4 s0 = __builtin_amdgcn_mfma_f32_16x16x32_bf16(qfrag, k0, zf, 0, 0, 0);
      if (nw24) {
        const bf16x8 k1 = *(const bf16x8*)&Ks[cur][16 + ll][lh * 8];
        f32x4 s1 = __builtin_amdgcn_mfma_f32_16x16x32_bf16(qfrag, k1, zf, 0, 0, 0);
#pragma unroll
        for (int r = 0; r < 4; ++r) {
          float e0 = exp2f(fmaf(s0[r], C2, rb + cb0[r]));
          float e1 = exp2f(fmaf(s1[r], C2, rb + cb1[r]));
          lsum[r] += e0 + e1;
          Ps[wv][(lh << 2) + r][ll]      = f2bf_rna(e0);
          Ps[wv][(lh << 2) + r][16 + ll] = f2bf_rna(e1);
        }
      } else {
#pragma unroll
        for (int r = 0; r < 4; ++r) {
          float e0 = exp2f(fmaf(s0[r], C2, rb + cb0[r]));
          lsum[r] += e0;
          Ps[wv][(lh << 2) + r][ll] = f2bf_rna(e0);
        }
      }
      const bf16x8 pa = *(const bf16x8*)&Ps[wv][ll][lh * 8];
      const bf16x8 v0 = *(const bf16x8*)&VTs[cur][ll][lh * 8];
      const bf16x8 v1 = *(const bf16x8*)&VTs[cur][16 + ll][lh * 8];
      o0 = __builtin_amdgcn_mfma_f32_16x16x32_bf16(pa, v0, o0, 0, 0, 0);
      o1 = __builtin_amdgcn_mfma_f32_16x16x32_bf16(pa, v1, o1, 0, 0, 0);
    }
    if (more) {
      *(ushort4*)&Ks[cur ^ 1][sk_key][sk_d] = nkv;
      *(ushort4*)&VTs[cur ^ 1][sv_d][sv_k] = nvv;
    }
    cur ^= 1;
  }

#pragma unroll
  for (int r = 0; r < 4; ++r) {
    float s = lsum[r];
    s += __shfl_xor(s, 1); s += __shfl_xor(s, 2);
    s += __shfl_xor(s, 4); s += __shfl_xor(s, 8);
    const float inv = 1.0f / s;
    const size_t row = ((size_t)b * NN + qh0 * WI + qw_r[r]) * CC + head * HD;
    Ob[row + ll]      = f2bf(o0[r] * inv);
    Ob[row + 16 + ll] = f2bf(o1[r] * inv);
  }
}

// ---------------------------------------------------------------------------
// GEMM 2 (64x64 tiles): RES[m][c] = bf16( O @ W2^T + b2 + x[b][c][n] )
// ---------------------------------------------------------------------------
__global__ __launch_bounds__(256) void outproj_gemm(
    const u16* __restrict__ Ob, const u16* __restrict__ W2b,
    const float* __restrict__ bias, const float* __restrict__ x,
    u16* __restrict__ RESb) {
  __shared__ u16 As[64][40];
  __shared__ u16 Ws[64][40];
  const int tid = threadIdx.x;
  const int m0 = blockIdx.x * 64, j0 = blockIdx.y * 64;
  f32x4 acc[2][2] = {};
  gemm_core64(Ob, W2b, m0, j0, As, Ws, acc, tid);

  const int lane = tid & 63, ll = lane & 15, lh = lane >> 4;
  const int wv = tid >> 6;
  const int wm = (wv >> 1) << 5, wj = (wv & 1) << 5;
  const int b = m0 / NN, n0 = m0 % NN;
#pragma unroll
  for (int js = 0; js < 2; ++js) {
    const int j = j0 + wj + js * 16 + ll;
    const float bj = bias[j];
#pragma unroll
    for (int ms = 0; ms < 2; ++ms) {
      const int nb = n0 + wm + ms * 16 + (lh << 2);
      float4 xr = *(const float4*)&x[((size_t)b * CC + j) * NN + nb];
      float rr[4] = {acc[ms][js][0] + bj + xr.x, acc[ms][js][1] + bj + xr.y,
                     acc[ms][js][2] + bj + xr.z, acc[ms][js][3] + bj + xr.w};
#pragma unroll
      for (int r = 0; r < 4; ++r)
        RESb[(size_t)(m0 + wm + ms * 16 + (lh << 2) + r) * CC + j] = f2bf(rr[r]);
    }
  }
}

// ---------------------------------------------------------------------------
// GEMM 3 (64x64 tiles): out[b][c][n] = relu( RES @ W3^T + b3 )  (fp32 output)
// ---------------------------------------------------------------------------
__global__ __launch_bounds__(256) void conv_gemm(
    const u16* __restrict__ RESb, const u16* __restrict__ W3b,
    const float* __restrict__ bias, float* __restrict__ out) {
  __shared__ u16 As[64][40];
  __shared__ u16 Ws[64][40];
  const int tid = threadIdx.x;
  const int m0 = blockIdx.x * 64, j0 = blockIdx.y * 64;
  f32x4 acc[2][2] = {};
  gemm_core64(RESb, W3b, m0, j0, As, Ws, acc, tid);

  const int lane = tid & 63, ll = lane & 15, lh = lane >> 4;
  const int wv = tid >> 6;
  const int wm = (wv >> 1) << 5, wj = (wv & 1) << 5;
  const int b = m0 / NN, n0 = m0 % NN;
#pragma unroll
  for (int js = 0; js < 2; ++js) {
    const int j = j0 + wj + js * 16 + ll;
    const float bj = bias[j];
#pragma unroll
    for (int ms = 0; ms < 2; ++ms) {
      const int nb = n0 + wm + ms * 16 + (lh << 2);
      float4 v;
      v.x = fmaxf(acc[ms][js][0] + bj, 0.0f);
      v.y = fmaxf(acc[ms][js][1] + bj, 0.0f);
      v.z = fmaxf(acc[ms][js][2] + bj, 0.0f);
      v.w = fmaxf(acc[ms][js][3] + bj, 0.0f);
      *(float4*)&out[((size_t)b * CC + j) * NN + nb] = v;
    }
  }
}

extern "C" void kernel_launch(void* const* d_in, const int* in_sizes, int n_in,
                              void* d_out, int out_size, void* d_ws, size_t ws_size,
                              hipStream_t stream) {
  const float* x         = (const float*)d_in[0];
  const float* in_proj_w = (const float*)d_in[1];
  const float* in_proj_b = (const float*)d_in[2];
  const float* out_w     = (const float*)d_in[3];
  const float* out_b     = (const float*)d_in[4];
  const float* conv_w    = (const float*)d_in[5];
  const float* conv_b    = (const float*)d_in[6];
  float* out = (float*)d_out;

  u16* wsb = (u16*)d_ws;
  u16* XT   = wsb;                         // [9216][256] bf16
  u16* Qb   = wsb + (size_t)BUF;           // [B,H,N,32]
  u16* Kb   = wsb + (size_t)2 * BUF;       // [B,H,N,32]
  u16* VTb  = wsb + (size_t)3 * BUF;       // [B,H,32,N]
  u16* Ob   = wsb + (size_t)4 * BUF;       // [9216][256]
  u16* RESb = wsb + (size_t)5 * BUF;       // [9216][256]
  u16* W1b  = wsb + (size_t)6 * BUF;       // [768][256]
  u16* W2b  = W1b + 196608;                // [256][256]
  u16* W3b  = W2b + 65536;                 // [256][256]

  prep_kernel<<<dim3(2624), dim3(256), 0, stream>>>(x, in_proj_w, out_w, conv_w,
                                                    XT, W1b, W2b, W3b);
  qkv_gemm<<<dim3(144, 12), dim3(256), 0, stream>>>(XT, W1b, in_proj_b, Qb, Kb, VTb);
  attn_mfma<<<dim3(1152), dim3(256), 0, stream>>>(Qb, Kb, VTb, Ob);
  outproj_gemm<<<dim3(144, 4), dim3(256), 0, stream>>>(Ob, W2b, out_b, x, RESb);
  conv_gemm<<<dim3(144, 4), dim3(256), 0, stream>>>(RESb, W3b, conv_b, out);
}

// Round 11
// 63.387 us; speedup vs baseline: 1.2092x; 1.0633x over previous
//
#include <hip/hip_runtime.h>
#include <math.h>

#define BB 4
#define CC 256
#define HH 48
#define WI 48
#define NN (HH*WI)      // 2304
#define NHEAD 8
#define HD 32
#define PLANE ((size_t)NN*HD)
#define BUF   (BB*NHEAD*NN*HD)      // 2359296 elems per [9216,256] buffer

typedef unsigned short u16;
typedef __attribute__((ext_vector_type(8))) short bf16x8;
typedef __attribute__((ext_vector_type(4))) float f32x4;

__device__ inline u16 f2bf(float f) {          // RNE float->bf16
  union { float f; unsigned u; } v; v.f = f;
  unsigned r = v.u + 0x7FFFu + ((v.u >> 16) & 1u);
  return (u16)(r >> 16);
}
__device__ inline u16 f2bf_rna(float f) {      // cheap round (f>=0)
  union { float f; unsigned u; } v; v.f = f;
  return (u16)((v.u + 0x8000u) >> 16);
}

// ---------------------------------------------------------------------------
// Fused prep: blocks [0,2304): XT[b*N+n][c] = bf16(x[b][c][n]) transpose tiles
//             blocks [2304,2624): fp32->bf16 weight convert (W1|W2|W3)
// ---------------------------------------------------------------------------
__global__ __launch_bounds__(256) void prep_kernel(
    const float* __restrict__ x, const float* __restrict__ w1,
    const float* __restrict__ w2, const float* __restrict__ w3,
    u16* __restrict__ XT, u16* __restrict__ W1b,
    u16* __restrict__ W2b, u16* __restrict__ W3b) {
  __shared__ float T[32][36];
  const int bx = blockIdx.x;
  const int t = threadIdx.x;
  if (bx < 2304) {
    const int n0 = (bx % 72) * 32, c0 = ((bx / 72) & 7) * 32, b = bx / 576;
    const int c = t >> 3, n4 = (t & 7) * 4;
    *(float4*)&T[c][n4] = *(const float4*)&x[((size_t)b * CC + c0 + c) * NN + n0 + n4];
    __syncthreads();
    const int nn = t >> 3, c4 = (t & 7) * 4;
    ushort4 o;
    o.x = f2bf(T[c4 + 0][nn]); o.y = f2bf(T[c4 + 1][nn]);
    o.z = f2bf(T[c4 + 2][nn]); o.w = f2bf(T[c4 + 3][nn]);
    *(ushort4*)&XT[((size_t)b * NN + n0 + nn) * CC + c0 + c4] = o;
  } else {
    const int i = ((bx - 2304) * 256 + t) * 4;
    const float* src; u16* dst; int off;
    if (i < 196608)      { src = w1; dst = W1b; off = i; }
    else if (i < 262144) { src = w2; dst = W2b; off = i - 196608; }
    else                 { src = w3; dst = W3b; off = i - 262144; }
    float4 v = *(const float4*)&src[off];
    ushort4 o = {f2bf(v.x), f2bf(v.y), f2bf(v.z), f2bf(v.w)};
    *(ushort4*)&dst[off] = o;
  }
}

// ---------------------------------------------------------------------------
// MFMA GEMM core 128x128 (R4/R8-proven, used by qkv): K=256, 4 waves 2x2.
// Frag layout (HW-verified): A row=ll, B col=ll, k=lh*8+j; C/D row=lh*4+r, col=ll.
// ---------------------------------------------------------------------------
__device__ __forceinline__ void gemm_core(
    const u16* __restrict__ act, const u16* __restrict__ wb,
    int m0, int j0, u16 (&As)[128][40], u16 (&Ws)[128][40],
    f32x4 (&acc)[4][4], int tid) {
  const int lane = tid & 63, ll = lane & 15, lh = lane >> 4;
  const int wv = tid >> 6;
  const int wm = (wv >> 1) << 6, wj = (wv & 1) << 6;
  const int r_ = tid >> 1;
  const int kh = (tid & 1) << 4;
  for (int k0 = 0; k0 < CC; k0 += 32) {
    __syncthreads();
    bf16x8 a0 = *(const bf16x8*)&act[(size_t)(m0 + r_) * CC + k0 + kh];
    bf16x8 a1 = *(const bf16x8*)&act[(size_t)(m0 + r_) * CC + k0 + kh + 8];
    bf16x8 w0 = *(const bf16x8*)&wb[(size_t)(j0 + r_) * CC + k0 + kh];
    bf16x8 w1 = *(const bf16x8*)&wb[(size_t)(j0 + r_) * CC + k0 + kh + 8];
    *(bf16x8*)&As[r_][kh]     = a0;
    *(bf16x8*)&As[r_][kh + 8] = a1;
    *(bf16x8*)&Ws[r_][kh]     = w0;
    *(bf16x8*)&Ws[r_][kh + 8] = w1;
    __syncthreads();
    bf16x8 af[4], bfv[4];
#pragma unroll
    for (int s = 0; s < 4; ++s) {
      af[s]  = *(const bf16x8*)&As[wm + s * 16 + ll][lh * 8];
      bfv[s] = *(const bf16x8*)&Ws[wj + s * 16 + ll][lh * 8];
    }
#pragma unroll
    for (int ms = 0; ms < 4; ++ms)
#pragma unroll
      for (int js = 0; js < 4; ++js)
        acc[ms][js] = __builtin_amdgcn_mfma_f32_16x16x32_bf16(af[ms], bfv[js], acc[ms][js], 0, 0, 0);
  }
}

// ---------------------------------------------------------------------------
// MFMA GEMM core 64x64 (outproj/conv). 4 waves 2x2, wave = 32x32. LDS 10 KB.
// ---------------------------------------------------------------------------
__device__ __forceinline__ void gemm_core64(
    const u16* __restrict__ act, const u16* __restrict__ wb,
    int m0, int j0, u16 (&As)[64][40], u16 (&Ws)[64][40],
    f32x4 (&acc)[2][2], int tid) {
  const int lane = tid & 63, ll = lane & 15, lh = lane >> 4;
  const int wv = tid >> 6;
  const int wm = (wv >> 1) << 5, wj = (wv & 1) << 5;
  const bool isW = (tid >= 128);
  const int r_ = (tid & 127) >> 1;
  const int kh = (tid & 1) << 4;
  const u16* src = isW ? &wb[(size_t)(j0 + r_) * CC + kh]
                       : &act[(size_t)(m0 + r_) * CC + kh];
  u16* dst = isW ? &Ws[r_][kh] : &As[r_][kh];
  for (int k0 = 0; k0 < CC; k0 += 32) {
    __syncthreads();
    bf16x8 v0 = *(const bf16x8*)(src + k0);
    bf16x8 v1 = *(const bf16x8*)(src + k0 + 8);
    *(bf16x8*)dst       = v0;
    *(bf16x8*)(dst + 8) = v1;
    __syncthreads();
    bf16x8 af[2], bfv[2];
#pragma unroll
    for (int s = 0; s < 2; ++s) {
      af[s]  = *(const bf16x8*)&As[wm + s * 16 + ll][lh * 8];
      bfv[s] = *(const bf16x8*)&Ws[wj + s * 16 + ll][lh * 8];
    }
#pragma unroll
    for (int ms = 0; ms < 2; ++ms)
#pragma unroll
      for (int js = 0; js < 2; ++js)
        acc[ms][js] = __builtin_amdgcn_mfma_f32_16x16x32_bf16(af[ms], bfv[js], acc[ms][js], 0, 0, 0);
  }
}

// ---------------------------------------------------------------------------
// GEMM 1 (128x128, R8 config): qkv = XT @ W1^T + b1 -> Q, K [B,H,N,32], VT [B,H,32,N]
// ---------------------------------------------------------------------------
__global__ __launch_bounds__(256) void qkv_gemm(
    const u16* __restrict__ XT, const u16* __restrict__ W1b,
    const float* __restrict__ bias,
    u16* __restrict__ Qb, u16* __restrict__ Kb, u16* __restrict__ VTb) {
  __shared__ u16 As[128][40];
  __shared__ u16 Ws[128][40];
  const int tid = threadIdx.x;
  const int m0 = blockIdx.x * 128, j0 = blockIdx.y * 128;
  f32x4 acc[4][4] = {};
  gemm_core(XT, W1b, m0, j0, As, Ws, acc, tid);

  const int lane = tid & 63, ll = lane & 15, lh = lane >> 4;
  const int wv = tid >> 6;
  const int wm = (wv >> 1) << 6, wj = (wv & 1) << 6;
  const int part = blockIdx.y >> 1;            // 0=Q 1=K 2=V (uniform)
  const int b = m0 / NN, n0 = m0 % NN;
#pragma unroll
  for (int js = 0; js < 4; ++js) {
    const int j = j0 + wj + js * 16 + ll;
    const float bj = bias[j];
    const int head = (j >> 5) & 7, d = j & 31;
#pragma unroll
    for (int ms = 0; ms < 4; ++ms) {
      const int nb = n0 + wm + ms * 16 + (lh << 2);
      if (part == 2) {
        ushort4 v = {f2bf(acc[ms][js][0] + bj), f2bf(acc[ms][js][1] + bj),
                     f2bf(acc[ms][js][2] + bj), f2bf(acc[ms][js][3] + bj)};
        *(ushort4*)&VTb[(((size_t)b * NHEAD + head) * HD + d) * NN + nb] = v;
      } else {
        u16* dst = (part == 0 ? Qb : Kb) + ((size_t)b * NHEAD + head) * PLANE;
#pragma unroll
        for (int r = 0; r < 4; ++r)
          dst[(size_t)(nb + r) * HD + d] = f2bf(acc[ms][js][r] + bj);
      }
    }
  }
}

// ---------------------------------------------------------------------------
// MFMA windowed attention, 16x4 query tile: wave = ONE spatial query row of
// 16 queries. Key window = 20 rows x <=32 cols (fits 32-key slots exactly).
// Row mask eliminated (loop bounds == window); one uniform code path.
// Block-staged K/V, double-buffered, 1 barrier/row (R8-proven structure).
// ---------------------------------------------------------------------------
__global__ __launch_bounds__(256) void attn_mfma(
    const u16* __restrict__ Qb, const u16* __restrict__ Kb,
    const u16* __restrict__ VTb, u16* __restrict__ Ob) {
  __shared__ u16 Ks[2][32][32];   // [buf][keyslot][dim]
  __shared__ u16 VTs[2][32][40];  // [buf][dim][keyslot]
  __shared__ u16 Ps[4][16][40];   // per-wave P [query][keyslot]
  const int bid  = blockIdx.x;
  const int tile = bid % 36;      // 12 (th) x 3 (tw)
  const int head = (bid / 36) & 7;
  const int b    = bid / 288;
  const int th0 = (tile / 3) * 4, tw0 = (tile % 3) * 16;
  const int tid = threadIdx.x;
  const int wv = tid >> 6, lane = tid & 63;
  const int lh = lane >> 4, ll = lane & 15;
  const size_t plane = ((size_t)b * NHEAD + head) * PLANE;

  const int wlo = max(0, tw0 - 8);
  const int nw  = min(WI, tw0 + 24) - wlo;       // 24 or 32, block-uniform
  const int rlo = max(0, th0 - 8), rhi = min(HH, th0 + 12);   // <=20 rows

  const int qh = th0 + wv;                       // wave's query row
  // Q A-frag: row ll -> query col tw0+ll; k = lh*8+j
  const bf16x8 qfrag = *(const bf16x8*)&Qb[plane + (size_t)(qh * WI + tw0 + ll) * HD + lh * 8];

  // column masks per C/D reg r (query col = tw0 + lh*4 + r)
  int qw_r[4];
  float cb0[4], cb1[4];
  const int wk0 = wlo + ll;            // <= 39, always a real column
  const int wk1 = wlo + 16 + ll;       // may be >= 48 for tw0=32
#pragma unroll
  for (int r = 0; r < 4; ++r) {
    qw_r[r] = tw0 + (lh << 2) + r;
    cb0[r] = (abs(wk0 - qw_r[r]) <= 8) ? 0.0f : -30000.0f;
    cb1[r] = (wk1 < WI && abs(wk1 - qw_r[r]) <= 8) ? 0.0f : -30000.0f;
  }

  f32x4 o0 = {0.f, 0.f, 0.f, 0.f}, o1 = {0.f, 0.f, 0.f, 0.f};
  const f32x4 zf = {0.f, 0.f, 0.f, 0.f};
  float lsum[4] = {0.f, 0.f, 0.f, 0.f};
  const int sk_key = tid >> 3, sk_d = (tid & 7) * 4;   // K staging (32x32)
  const int sv_d   = tid >> 3, sv_k = (tid & 7) * 4;   // VT staging (32x32)
  const ushort4 zz = {0, 0, 0, 0};
  const float C2 = 0.25501651847296056f;         // (1/sqrt(32)) * log2(e)

  // stage first row into buf 0
  {
    ushort4 kv = zz, vv = zz;
    if (sk_key < nw)
      kv = *(const ushort4*)&Kb[plane + (size_t)(rlo * WI + wlo + sk_key) * HD + sk_d];
    if (sv_k < nw)
      vv = *(const ushort4*)&VTb[plane + (size_t)sv_d * NN + rlo * WI + wlo + sv_k];
    *(ushort4*)&Ks[0][sk_key][sk_d] = kv;
    *(ushort4*)&VTs[0][sv_d][sv_k] = vv;
  }

  int cur = 0;
  for (int hk = rlo; hk < rhi; ++hk) {
    ushort4 nkv = zz, nvv = zz;
    const bool more = (hk + 1 < rhi);
    if (more) {
      if (sk_key < nw)
        nkv = *(const ushort4*)&Kb[plane + (size_t)((hk + 1) * WI + wlo + sk_key) * HD + sk_d];
      if (sv_k < nw)
        nvv = *(const ushort4*)&VTb[plane + (size_t)sv_d * NN + (hk + 1) * WI + wlo + sv_k];
    }
    __syncthreads();   // buf[cur] complete
    if (hk >= qh - 8 && hk <= qh + 8) {            // wave-uniform, == row window
      const bf16x8 k0 = *(const bf16x8*)&Ks[cur][ll][lh * 8];
      const bf16x8 k1 = *(const bf16x8*)&Ks[cur][16 + ll][lh * 8];
      f32x4 s0 = __builtin_amdgcn_mfma_f32_16x16x32_bf16(qfrag, k0, zf, 0, 0, 0);
      f32x4 s1 = __builtin_amdgcn_mfma_f32_16x16x32_bf16(qfrag, k1, zf, 0, 0, 0);
#pragma unroll
      for (int r = 0; r < 4; ++r) {
        float e0 = exp2f(fmaf(s0[r], C2, cb0[r]));
        float e1 = exp2f(fmaf(s1[r], C2, cb1[r]));
        lsum[r] += e0 + e1;
        Ps[wv][(lh << 2) + r][ll]      = f2bf_rna(e0);
        Ps[wv][(lh << 2) + r][16 + ll] = f2bf_rna(e1);
      }
      const bf16x8 pa = *(const bf16x8*)&Ps[wv][ll][lh * 8];
      const bf16x8 v0 = *(const bf16x8*)&VTs[cur][ll][lh * 8];
      const bf16x8 v1 = *(const bf16x8*)&VTs[cur][16 + ll][lh * 8];
      o0 = __builtin_amdgcn_mfma_f32_16x16x32_bf16(pa, v0, o0, 0, 0, 0);
      o1 = __builtin_amdgcn_mfma_f32_16x16x32_bf16(pa, v1, o1, 0, 0, 0);
    }
    if (more) {
      *(ushort4*)&Ks[cur ^ 1][sk_key][sk_d] = nkv;
      *(ushort4*)&VTs[cur ^ 1][sv_d][sv_k] = nvv;
    }
    cur ^= 1;
  }

#pragma unroll
  for (int r = 0; r < 4; ++r) {
    float s = lsum[r];
    s += __shfl_xor(s, 1); s += __shfl_xor(s, 2);
    s += __shfl_xor(s, 4); s += __shfl_xor(s, 8);
    const float inv = 1.0f / s;
    const size_t row = ((size_t)b * NN + qh * WI + qw_r[r]) * CC + head * HD;
    Ob[row + ll]      = f2bf(o0[r] * inv);
    Ob[row + 16 + ll] = f2bf(o1[r] * inv);
  }
}

// ---------------------------------------------------------------------------
// GEMM 2 (64x64 tiles): RES[m][c] = bf16( O @ W2^T + b2 + x[b][c][n] )
// ---------------------------------------------------------------------------
__global__ __launch_bounds__(256) void outproj_gemm(
    const u16* __restrict__ Ob, const u16* __restrict__ W2b,
    const float* __restrict__ bias, const float* __restrict__ x,
    u16* __restrict__ RESb) {
  __shared__ u16 As[64][40];
  __shared__ u16 Ws[64][40];
  const int tid = threadIdx.x;
  const int m0 = blockIdx.x * 64, j0 = blockIdx.y * 64;
  f32x4 acc[2][2] = {};
  gemm_core64(Ob, W2b, m0, j0, As, Ws, acc, tid);

  const int lane = tid & 63, ll = lane & 15, lh = lane >> 4;
  const int wv = tid >> 6;
  const int wm = (wv >> 1) << 5, wj = (wv & 1) << 5;
  const int b = m0 / NN, n0 = m0 % NN;
#pragma unroll
  for (int js = 0; js < 2; ++js) {
    const int j = j0 + wj + js * 16 + ll;
    const float bj = bias[j];
#pragma unroll
    for (int ms = 0; ms < 2; ++ms) {
      const int nb = n0 + wm + ms * 16 + (lh << 2);
      float4 xr = *(const float4*)&x[((size_t)b * CC + j) * NN + nb];
      float rr[4] = {acc[ms][js][0] + bj + xr.x, acc[ms][js][1] + bj + xr.y,
                     acc[ms][js][2] + bj + xr.z, acc[ms][js][3] + bj + xr.w};
#pragma unroll
      for (int r = 0; r < 4; ++r)
        RESb[(size_t)(m0 + wm + ms * 16 + (lh << 2) + r) * CC + j] = f2bf(rr[r]);
    }
  }
}

// ---------------------------------------------------------------------------
// GEMM 3 (64x64 tiles): out[b][c][n] = relu( RES @ W3^T + b3 )  (fp32 output)
// ---------------------------------------------------------------------------
__global__ __launch_bounds__(256) void conv_gemm(
    const u16* __restrict__ RESb, const u16* __restrict__ W3b,
    const float* __restrict__ bias, float* __restrict__ out) {
  __shared__ u16 As[64][40];
  __shared__ u16 Ws[64][40];
  const int tid = threadIdx.x;
  const int m0 = blockIdx.x * 64, j0 = blockIdx.y * 64;
  f32x4 acc[2][2] = {};
  gemm_core64(RESb, W3b, m0, j0, As, Ws, acc, tid);

  const int lane = tid & 63, ll = lane & 15, lh = lane >> 4;
  const int wv = tid >> 6;
  const int wm = (wv >> 1) << 5, wj = (wv & 1) << 5;
  const int b = m0 / NN, n0 = m0 % NN;
#pragma unroll
  for (int js = 0; js < 2; ++js) {
    const int j = j0 + wj + js * 16 + ll;
    const float bj = bias[j];
#pragma unroll
    for (int ms = 0; ms < 2; ++ms) {
      const int nb = n0 + wm + ms * 16 + (lh << 2);
      float4 v;
      v.x = fmaxf(acc[ms][js][0] + bj, 0.0f);
      v.y = fmaxf(acc[ms][js][1] + bj, 0.0f);
      v.z = fmaxf(acc[ms][js][2] + bj, 0.0f);
      v.w = fmaxf(acc[ms][js][3] + bj, 0.0f);
      *(float4*)&out[((size_t)b * CC + j) * NN + nb] = v;
    }
  }
}

extern "C" void kernel_launch(void* const* d_in, const int* in_sizes, int n_in,
                              void* d_out, int out_size, void* d_ws, size_t ws_size,
                              hipStream_t stream) {
  const float* x         = (const float*)d_in[0];
  const float* in_proj_w = (const float*)d_in[1];
  const float* in_proj_b = (const float*)d_in[2];
  const float* out_w     = (const float*)d_in[3];
  const float* out_b     = (const float*)d_in[4];
  const float* conv_w    = (const float*)d_in[5];
  const float* conv_b    = (const float*)d_in[6];
  float* out = (float*)d_out;

  u16* wsb = (u16*)d_ws;
  u16* XT   = wsb;                         // [9216][256] bf16
  u16* Qb   = wsb + (size_t)BUF;           // [B,H,N,32]
  u16* Kb   = wsb + (size_t)2 * BUF;       // [B,H,N,32]
  u16* VTb  = wsb + (size_t)3 * BUF;       // [B,H,32,N]
  u16* Ob   = wsb + (size_t)4 * BUF;       // [9216][256]
  u16* RESb = wsb + (size_t)5 * BUF;       // [9216][256]
  u16* W1b  = wsb + (size_t)6 * BUF;       // [768][256]
  u16* W2b  = W1b + 196608;                // [256][256]
  u16* W3b  = W2b + 65536;                 // [256][256]

  prep_kernel<<<dim3(2624), dim3(256), 0, stream>>>(x, in_proj_w, out_w, conv_w,
                                                    XT, W1b, W2b, W3b);
  qkv_gemm<<<dim3(72, 6), dim3(256), 0, stream>>>(XT, W1b, in_proj_b, Qb, Kb, VTb);
  attn_mfma<<<dim3(1152), dim3(256), 0, stream>>>(Qb, Kb, VTb, Ob);
  outproj_gemm<<<dim3(144, 4), dim3(256), 0, stream>>>(Ob, W2b, out_b, x, RESb);
  conv_gemm<<<dim3(144, 4), dim3(256), 0, stream>>>(RESb, W3b, conv_b, out);
}